// Round 1
// baseline (1738.151 us; speedup 1.0000x reference)
//
#include <hip/hip_runtime.h>

#define NN 50000
#define NE 800000

// ---------------- graph degree / dinv ----------------
__global__ void k_deg(const int* __restrict__ dst, float* __restrict__ deg) {
  int e = blockIdx.x * 256 + threadIdx.x;
  if (e < NE) atomicAdd(&deg[dst[e]], 1.0f);
}

__global__ void k_dinv(float* deg) {
  int i = blockIdx.x * 256 + threadIdx.x;
  if (i < NN) deg[i] = rsqrtf(deg[i] + 2.0f);
}

// ---------------- weight composition (tiny) ----------------
// Wc2 = w2@fw2 [32,64], Wc3 = w3@fw3 [64,128], bc1=b1@fw1+fb1, bc2, bc3
__global__ void k_prep_misc(const float* __restrict__ w2, const float* __restrict__ fw2,
                            const float* __restrict__ w3, const float* __restrict__ fw3,
                            const float* __restrict__ b1, const float* __restrict__ fw1,
                            const float* __restrict__ fb1,
                            const float* __restrict__ b2, const float* __restrict__ fb2,
                            const float* __restrict__ b3, const float* __restrict__ fb3,
                            float* __restrict__ Wc2, float* __restrict__ Wc3,
                            float* __restrict__ bc1, float* __restrict__ bc2,
                            float* __restrict__ bc3) {
  int id = blockIdx.x * 256 + threadIdx.x;
  if (id < 2048) {                       // Wc2 [32,64]
    int c = id >> 6, k = id & 63;
    float s = 0.f;
    for (int j = 0; j < 64; ++j) s = fmaf(w2[c * 64 + j], fw2[j * 64 + k], s);
    Wc2[id] = s;
  } else if (id < 10240) {               // Wc3 [64,128]
    int idx = id - 2048;
    int c = idx >> 7, k = idx & 127;
    float s = 0.f;
    for (int j = 0; j < 128; ++j) s = fmaf(w3[c * 128 + j], fw3[j * 128 + k], s);
    Wc3[idx] = s;
  } else if (id < 10272) {               // bc1 [32]
    int k = id - 10240;
    float s = fb1[k];
    for (int j = 0; j < 32; ++j) s = fmaf(b1[j], fw1[j * 32 + k], s);
    bc1[k] = s;
  } else if (id < 10336) {               // bc2 [64]
    int k = id - 10272;
    float s = fb2[k];
    for (int j = 0; j < 64; ++j) s = fmaf(b2[j], fw2[j * 64 + k], s);
    bc2[k] = s;
  } else if (id < 10464) {               // bc3 [128]
    int k = id - 10336;
    float s = fb3[k];
    for (int j = 0; j < 128; ++j) s = fmaf(b3[j], fw3[j * 128 + k], s);
    bc3[k] = s;
  }
}

// G[c*4+l, k] = sum_{o<32,t<2} wd3[c,o,t] * wf[o*8+2l+t, k]   (d2-flat -> out)
__global__ void k_prep_G(const float* __restrict__ wd3, const float* __restrict__ wf,
                         float* __restrict__ G) {
  int id = blockIdx.x * 256 + threadIdx.x;
  if (id >= 16384) return;
  int k = id & 127, r = id >> 7;
  int c = r >> 2, l = r & 3;
  float s = 0.f;
  for (int o = 0; o < 32; ++o) {
    s = fmaf(wd3[c * 64 + o * 2 + 0], wf[(o * 8 + 2 * l + 0) * 128 + k], s);
    s = fmaf(wd3[c * 64 + o * 2 + 1], wf[(o * 8 + 2 * l + 1) * 128 + k], s);
  }
  G[r * 128 + k] = s;
}

// H[c*2+l, k] = sum_{o<32,t<2} wd2[c,o,t] * G[o*4+2l+t, k]   (d1-flat -> out)
// A1[c,k] = sum_{o<32} ws2[c,o] * sum_{p<4} G[o*4+p, k]
__global__ void k_prep_HA1(const float* __restrict__ wd2, const float* __restrict__ G,
                           const float* __restrict__ ws2,
                           float* __restrict__ Hm, float* __restrict__ A1) {
  int id = blockIdx.x * 256 + threadIdx.x;
  if (id < 16384) {
    int k = id & 127, r = id >> 7;
    int c = r >> 1, l = r & 1;
    float s = 0.f;
    for (int o = 0; o < 32; ++o) {
      s = fmaf(wd2[c * 64 + o * 2 + 0], G[(o * 4 + 2 * l + 0) * 128 + k], s);
      s = fmaf(wd2[c * 64 + o * 2 + 1], G[(o * 4 + 2 * l + 1) * 128 + k], s);
    }
    Hm[r * 128 + k] = s;
  } else if (id < 16384 + 4096) {
    int idx = id - 16384;
    int k = idx & 127, c = idx >> 7;   // c < 32
    float s = 0.f;
    for (int o = 0; o < 32; ++o) {
      float g = G[(4 * o) * 128 + k] + G[(4 * o + 1) * 128 + k] +
                G[(4 * o + 2) * 128 + k] + G[(4 * o + 3) * 128 + k];
      s = fmaf(ws2[c * 32 + o], g, s);
    }
    A1[c * 128 + k] = s;
  }
}

// A3[c,k] = sum_j wd1flat[c*128+j] * H[j,k];  A2[c,k] = sum_o ws1[c,o]*(H[2o,k]+H[2o+1,k])
// c0[k] = beta1@H + beta2@G + bd3-term + bf
__global__ void k_prep_A32c0(const float* __restrict__ wd1, const float* __restrict__ ws1,
                             const float* __restrict__ Hm, const float* __restrict__ G,
                             const float* __restrict__ wf,
                             const float* __restrict__ bd1, const float* __restrict__ bs1,
                             const float* __restrict__ bd2, const float* __restrict__ bs2,
                             const float* __restrict__ bd3, const float* __restrict__ bf,
                             float* __restrict__ A3, float* __restrict__ A2,
                             float* __restrict__ c0) {
  int id = blockIdx.x * 256 + threadIdx.x;
  if (id < 16384) {
    int k = id & 127, c = id >> 7;
    float s = 0.f;
    for (int j = 0; j < 128; ++j) s = fmaf(wd1[c * 128 + j], Hm[j * 128 + k], s);
    A3[c * 128 + k] = s;
  } else if (id < 16384 + 8192) {
    int idx = id - 16384;
    int k = idx & 127, c = idx >> 7;   // c < 64
    float s = 0.f;
    for (int o = 0; o < 64; ++o)
      s = fmaf(ws1[c * 64 + o], Hm[(2 * o) * 128 + k] + Hm[(2 * o + 1) * 128 + k], s);
    A2[c * 128 + k] = s;
  } else if (id < 16384 + 8192 + 128) {
    int k = id - 16384 - 8192;
    float s = bf[k];
    for (int o = 0; o < 64; ++o) {
      float b = bd1[o] + bs1[o];
      s = fmaf(b, Hm[(o * 2) * 128 + k] + Hm[(o * 2 + 1) * 128 + k], s);
    }
    for (int o = 0; o < 32; ++o) {
      float b = bd2[o] + bs2[o];
      float g = G[(o * 4) * 128 + k] + G[(o * 4 + 1) * 128 + k] +
                G[(o * 4 + 2) * 128 + k] + G[(o * 4 + 3) * 128 + k];
      s = fmaf(b, g, s);
    }
    for (int o = 0; o < 32; ++o) {
      float w8 = 0.f;
      for (int j = 0; j < 8; ++j) w8 += wf[(o * 8 + j) * 128 + k];
      s = fmaf(bd3[o], w8, s);
    }
    c0[k] = s;
  }
}

// ---------------- per-node GEMM, W staged in LDS ----------------
// Y[n,k] = act( sum_c X[n,c]*W[c,k] + bias[k] );  optionally Z[n,k] = 2*dinv[n]^2 * Y[n,k]
template <int CIN, int COUT, bool BIAS, bool RELU, bool ZINIT>
__launch_bounds__(256)
__global__ void k_gemm(const float* __restrict__ X, const float* __restrict__ W,
                       const float* __restrict__ bias, float* __restrict__ Y,
                       float* __restrict__ Z, const float* __restrict__ dinv) {
  static_assert(256 % COUT == 0, "");
  __shared__ float sW[CIN * COUT];
  for (int i = threadIdx.x; i < CIN * COUT; i += 256) sW[i] = W[i];
  __syncthreads();
  constexpr int RPB = 256 / COUT;
  int k = threadIdx.x % COUT;
  int r = threadIdx.x / COUT;
  int n = blockIdx.x * RPB + r;
  if (n >= NN) return;
  const float* xr = X + (size_t)n * CIN;
  float acc = BIAS ? bias[k] : 0.0f;
#pragma unroll
  for (int c4 = 0; c4 < CIN / 4; ++c4) {
    float4 xv = *reinterpret_cast<const float4*>(xr + c4 * 4);
    acc = fmaf(xv.x, sW[(c4 * 4 + 0) * COUT + k], acc);
    acc = fmaf(xv.y, sW[(c4 * 4 + 1) * COUT + k], acc);
    acc = fmaf(xv.z, sW[(c4 * 4 + 2) * COUT + k], acc);
    acc = fmaf(xv.w, sW[(c4 * 4 + 3) * COUT + k], acc);
  }
  if (RELU) acc = fmaxf(acc, 0.0f);
  Y[(size_t)n * COUT + k] = acc;
  if (ZINIT) {
    float dv = dinv[n];
    Z[(size_t)n * COUT + k] = 2.0f * dv * dv * acc;
  }
}

// ---------------- edge aggregation: Z[dst] += dinv[src]*dinv[dst]*H[src] ----------------
template <int F>
__launch_bounds__(256)
__global__ void k_agg(const float* __restrict__ Hs, const int* __restrict__ srcv,
                      const int* __restrict__ dstv, const float* __restrict__ dinv,
                      float* __restrict__ Z) {
  constexpr int FG = F / 4;  // float4 groups per edge
  int gid = blockIdx.x * 256 + threadIdx.x;
  if (gid >= NE * FG) return;
  int e = gid / FG;
  int f4 = (gid % FG) * 4;
  int s = srcv[e], d = dstv[e];
  float coef = dinv[s] * dinv[d];
  float4 hv = *reinterpret_cast<const float4*>(Hs + (size_t)s * F + f4);
  float* zp = Z + (size_t)d * F + f4;
  atomicAdd(zp + 0, coef * hv.x);
  atomicAdd(zp + 1, coef * hv.y);
  atomicAdd(zp + 2, coef * hv.z);
  atomicAdd(zp + 3, coef * hv.w);
}

// ---------------- fused decoder: out = x3@A3 + x2@A2 + x1@A1 + c0 ----------------
// x3 lives in `io` (= d_out); rows are staged to LDS before being overwritten.
__launch_bounds__(256)
__global__ void k_final(const float* __restrict__ x1, const float* __restrict__ x2,
                        const float* __restrict__ A1, const float* __restrict__ A2,
                        const float* __restrict__ A3, const float* __restrict__ c0,
                        float* __restrict__ io) {
  __shared__ float sx3[8][128];
  __shared__ float sx2[8][64];
  __shared__ float sx1[8][32];
  int n0 = blockIdx.x * 8;
  for (int i = threadIdx.x; i < 8 * 128; i += 256)
    sx3[i >> 7][i & 127] = io[(size_t)(n0 + (i >> 7)) * 128 + (i & 127)];
  for (int i = threadIdx.x; i < 8 * 64; i += 256)
    sx2[i >> 6][i & 63] = x2[(size_t)(n0 + (i >> 6)) * 64 + (i & 63)];
  for (int i = threadIdx.x; i < 8 * 32; i += 256)
    sx1[i >> 5][i & 31] = x1[(size_t)(n0 + (i >> 5)) * 32 + (i & 31)];
  __syncthreads();
  int lane = threadIdx.x & 31;
  int r = threadIdx.x >> 5;  // row 0..7
  int k = lane * 4;
  float4 acc = *reinterpret_cast<const float4*>(c0 + k);
#pragma unroll 4
  for (int c = 0; c < 128; ++c) {
    float xv = sx3[r][c];
    float4 a = *reinterpret_cast<const float4*>(A3 + c * 128 + k);
    acc.x = fmaf(xv, a.x, acc.x);
    acc.y = fmaf(xv, a.y, acc.y);
    acc.z = fmaf(xv, a.z, acc.z);
    acc.w = fmaf(xv, a.w, acc.w);
  }
#pragma unroll 4
  for (int c = 0; c < 64; ++c) {
    float xv = sx2[r][c];
    float4 a = *reinterpret_cast<const float4*>(A2 + c * 128 + k);
    acc.x = fmaf(xv, a.x, acc.x);
    acc.y = fmaf(xv, a.y, acc.y);
    acc.z = fmaf(xv, a.z, acc.z);
    acc.w = fmaf(xv, a.w, acc.w);
  }
#pragma unroll 4
  for (int c = 0; c < 32; ++c) {
    float xv = sx1[r][c];
    float4 a = *reinterpret_cast<const float4*>(A1 + c * 128 + k);
    acc.x = fmaf(xv, a.x, acc.x);
    acc.y = fmaf(xv, a.y, acc.y);
    acc.z = fmaf(xv, a.z, acc.z);
    acc.w = fmaf(xv, a.w, acc.w);
  }
  *reinterpret_cast<float4*>(io + (size_t)(n0 + r) * 128 + k) = acc;
}

extern "C" void kernel_launch(void* const* d_in, const int* in_sizes, int n_in,
                              void* d_out, int out_size, void* d_ws, size_t ws_size,
                              hipStream_t stream) {
  const float* x   = (const float*)d_in[0];
  const int* ei    = (const int*)d_in[1];
  const int* srcv  = ei;
  const int* dstv  = ei + NE;
  const float* w1  = (const float*)d_in[2];
  const float* b1  = (const float*)d_in[3];
  const float* fw1 = (const float*)d_in[4];
  const float* fb1 = (const float*)d_in[5];
  const float* w2  = (const float*)d_in[6];
  const float* b2  = (const float*)d_in[7];
  const float* fw2 = (const float*)d_in[8];
  const float* fb2 = (const float*)d_in[9];
  const float* w3  = (const float*)d_in[10];
  const float* b3  = (const float*)d_in[11];
  const float* fw3 = (const float*)d_in[12];
  const float* fb3 = (const float*)d_in[13];
  const float* wd1 = (const float*)d_in[14];
  const float* bd1 = (const float*)d_in[15];
  const float* wd2 = (const float*)d_in[16];
  const float* bd2 = (const float*)d_in[17];
  const float* wd3 = (const float*)d_in[18];
  const float* bd3 = (const float*)d_in[19];
  const float* ws1 = (const float*)d_in[20];
  const float* bs1 = (const float*)d_in[21];
  const float* ws2 = (const float*)d_in[22];
  const float* bs2 = (const float*)d_in[23];
  const float* wf  = (const float*)d_in[24];
  const float* bf  = (const float*)d_in[25];

  float* ws = (float*)d_ws;
  float* dinv = ws;                 // 50048
  float* h1   = dinv + 50048;       // N*32
  float* z1   = h1 + 1600000;       // N*32
  float* x1   = z1 + 1600000;       // N*32
  float* z2   = x1 + 1600000;       // N*32
  float* x2   = z2 + 1600000;       // N*64
  float* z3   = x2 + 3200000;       // N*64
  float* Wc2  = z3 + 3200000;       // 2048
  float* Wc3  = Wc2 + 2048;         // 8192
  float* bc1  = Wc3 + 8192;         // 32
  float* bc2  = bc1 + 32;           // 64
  float* bc3  = bc2 + 64;           // 128
  float* G    = bc3 + 128;          // 16384
  float* Hm   = G + 16384;          // 16384
  float* A3   = Hm + 16384;         // 16384
  float* A2   = A3 + 16384;         // 8192
  float* A1   = A2 + 8192;          // 4096
  float* c0   = A1 + 4096;          // 128
  float* outp = (float*)d_out;      // x3 staged here, then final out

  hipMemsetAsync(dinv, 0, NN * sizeof(float), stream);
  k_deg<<<(NE + 255) / 256, 256, 0, stream>>>(dstv, dinv);
  k_dinv<<<(NN + 255) / 256, 256, 0, stream>>>(dinv);

  k_prep_misc<<<41, 256, 0, stream>>>(w2, fw2, w3, fw3, b1, fw1, fb1, b2, fb2, b3, fb3,
                                      Wc2, Wc3, bc1, bc2, bc3);
  k_prep_G<<<64, 256, 0, stream>>>(wd3, wf, G);
  k_prep_HA1<<<80, 256, 0, stream>>>(wd2, G, ws2, Hm, A1);
  k_prep_A32c0<<<97, 256, 0, stream>>>(wd1, ws1, Hm, G, wf, bd1, bs1, bd2, bs2, bd3, bf,
                                       A3, A2, c0);

  // Layer 1: h1 = x@w1; z1 = 2*dinv^2*h1; z1 += edges(h1); x1 = relu(z1@fw1 + bc1); z2init
  k_gemm<128, 32, false, false, true><<<NN / 8, 256, 0, stream>>>(x, w1, nullptr, h1, z1, dinv);
  k_agg<32><<<NE * 8 / 256, 256, 0, stream>>>(h1, srcv, dstv, dinv, z1);
  k_gemm<32, 32, true, true, true><<<NN / 8, 256, 0, stream>>>(z1, fw1, bc1, x1, z2, dinv);

  // Layer 2 (aggregate-first): z2 += edges(x1); x2 = relu(z2@Wc2 + bc2); z3init
  k_agg<32><<<NE * 8 / 256, 256, 0, stream>>>(x1, srcv, dstv, dinv, z2);
  k_gemm<32, 64, true, true, true><<<NN / 4, 256, 0, stream>>>(z2, Wc2, bc2, x2, z3, dinv);

  // Layer 3 (aggregate-first): z3 += edges(x2); x3 = relu(z3@Wc3 + bc3) -> d_out
  k_agg<64><<<NE * 16 / 256, 256, 0, stream>>>(x2, srcv, dstv, dinv, z3);
  k_gemm<64, 128, true, true, false><<<NN / 2, 256, 0, stream>>>(z3, Wc3, bc3, outp, nullptr, dinv);

  // Fused decoder
  k_final<<<NN / 8, 256, 0, stream>>>(x1, x2, A1, A2, A3, c0, outp);
}

// Round 2
// 597.187 us; speedup vs baseline: 2.9106x; 2.9106x over previous
//
#include <hip/hip_runtime.h>

#define NN 50000
#define NE 800000
#define NBLK 196  // ceil(NN/256)

// ---------------- CSR build ----------------
__global__ void k_hist(const int* __restrict__ dst, int* __restrict__ deg) {
  int e = blockIdx.x * 256 + threadIdx.x;
  if (e < NE) atomicAdd(&deg[dst[e]], 1);
}

__global__ void k_blksum(const int* __restrict__ deg, int* __restrict__ blksum) {
  __shared__ int s[256];
  int n = blockIdx.x * 256 + threadIdx.x;
  s[threadIdx.x] = (n < NN) ? deg[n] : 0;
  __syncthreads();
  for (int off = 128; off > 0; off >>= 1) {
    if (threadIdx.x < off) s[threadIdx.x] += s[threadIdx.x + off];
    __syncthreads();
  }
  if (threadIdx.x == 0) blksum[blockIdx.x] = s[0];
}

__global__ void k_blkscan(const int* __restrict__ blksum, int* __restrict__ blkoff) {
  __shared__ int s[256];
  int t = threadIdx.x;
  int v0 = (t < NBLK) ? blksum[t] : 0;
  s[t] = v0;
  __syncthreads();
  for (int off = 1; off < 256; off <<= 1) {
    int v = (t >= off) ? s[t - off] : 0;
    __syncthreads();
    s[t] += v;
    __syncthreads();
  }
  if (t < NBLK) blkoff[t] = s[t] - v0;  // exclusive
}

__global__ void k_scan3(const int* __restrict__ deg, const int* __restrict__ blkoff,
                        int* __restrict__ row_start, int* __restrict__ cursor,
                        float* __restrict__ dinv) {
  __shared__ int s[256];
  int n = blockIdx.x * 256 + threadIdx.x;
  int d = (n < NN) ? deg[n] : 0;
  s[threadIdx.x] = d;
  __syncthreads();
  for (int off = 1; off < 256; off <<= 1) {
    int v = (threadIdx.x >= off) ? s[threadIdx.x - off] : 0;
    __syncthreads();
    s[threadIdx.x] += v;
    __syncthreads();
  }
  if (n < NN) {
    int rs = blkoff[blockIdx.x] + s[threadIdx.x] - d;
    row_start[n] = rs;
    cursor[n] = rs;
    dinv[n] = rsqrtf((float)d + 2.0f);
  }
  if (n == 0) row_start[NN] = NE;
}

__global__ void k_scatter(const int* __restrict__ srcv, const int* __restrict__ dstv,
                          const float* __restrict__ dinv, int* __restrict__ cursor,
                          int* __restrict__ esrc, float* __restrict__ ecoef) {
  int e = blockIdx.x * 256 + threadIdx.x;
  if (e >= NE) return;
  int s = srcv[e], d = dstv[e];
  int pos = atomicAdd(&cursor[d], 1);
  esrc[pos] = s;
  ecoef[pos] = dinv[s] * dinv[d];
}

// ---------------- weight composition (tiny) ----------------
__global__ void k_prep_misc(const float* __restrict__ w2, const float* __restrict__ fw2,
                            const float* __restrict__ w3, const float* __restrict__ fw3,
                            const float* __restrict__ b1, const float* __restrict__ fw1,
                            const float* __restrict__ fb1,
                            const float* __restrict__ b2, const float* __restrict__ fb2,
                            const float* __restrict__ b3, const float* __restrict__ fb3,
                            float* __restrict__ Wc2, float* __restrict__ Wc3,
                            float* __restrict__ bc1, float* __restrict__ bc2,
                            float* __restrict__ bc3) {
  int id = blockIdx.x * 256 + threadIdx.x;
  if (id < 2048) {                       // Wc2 [32,64]
    int c = id >> 6, k = id & 63;
    float s = 0.f;
    for (int j = 0; j < 64; ++j) s = fmaf(w2[c * 64 + j], fw2[j * 64 + k], s);
    Wc2[id] = s;
  } else if (id < 10240) {               // Wc3 [64,128]
    int idx = id - 2048;
    int c = idx >> 7, k = idx & 127;
    float s = 0.f;
    for (int j = 0; j < 128; ++j) s = fmaf(w3[c * 128 + j], fw3[j * 128 + k], s);
    Wc3[idx] = s;
  } else if (id < 10272) {               // bc1 [32]
    int k = id - 10240;
    float s = fb1[k];
    for (int j = 0; j < 32; ++j) s = fmaf(b1[j], fw1[j * 32 + k], s);
    bc1[k] = s;
  } else if (id < 10336) {               // bc2 [64]
    int k = id - 10272;
    float s = fb2[k];
    for (int j = 0; j < 64; ++j) s = fmaf(b2[j], fw2[j * 64 + k], s);
    bc2[k] = s;
  } else if (id < 10464) {               // bc3 [128]
    int k = id - 10336;
    float s = fb3[k];
    for (int j = 0; j < 128; ++j) s = fmaf(b3[j], fw3[j * 128 + k], s);
    bc3[k] = s;
  }
}

__global__ void k_prep_G(const float* __restrict__ wd3, const float* __restrict__ wf,
                         float* __restrict__ G) {
  int id = blockIdx.x * 256 + threadIdx.x;
  if (id >= 16384) return;
  int k = id & 127, r = id >> 7;
  int c = r >> 2, l = r & 3;
  float s = 0.f;
  for (int o = 0; o < 32; ++o) {
    s = fmaf(wd3[c * 64 + o * 2 + 0], wf[(o * 8 + 2 * l + 0) * 128 + k], s);
    s = fmaf(wd3[c * 64 + o * 2 + 1], wf[(o * 8 + 2 * l + 1) * 128 + k], s);
  }
  G[r * 128 + k] = s;
}

__global__ void k_prep_HA1(const float* __restrict__ wd2, const float* __restrict__ G,
                           const float* __restrict__ ws2,
                           float* __restrict__ Hm, float* __restrict__ A1) {
  int id = blockIdx.x * 256 + threadIdx.x;
  if (id < 16384) {
    int k = id & 127, r = id >> 7;
    int c = r >> 1, l = r & 1;
    float s = 0.f;
    for (int o = 0; o < 32; ++o) {
      s = fmaf(wd2[c * 64 + o * 2 + 0], G[(o * 4 + 2 * l + 0) * 128 + k], s);
      s = fmaf(wd2[c * 64 + o * 2 + 1], G[(o * 4 + 2 * l + 1) * 128 + k], s);
    }
    Hm[r * 128 + k] = s;
  } else if (id < 16384 + 4096) {
    int idx = id - 16384;
    int k = idx & 127, c = idx >> 7;   // c < 32
    float s = 0.f;
    for (int o = 0; o < 32; ++o) {
      float g = G[(4 * o) * 128 + k] + G[(4 * o + 1) * 128 + k] +
                G[(4 * o + 2) * 128 + k] + G[(4 * o + 3) * 128 + k];
      s = fmaf(ws2[c * 32 + o], g, s);
    }
    A1[c * 128 + k] = s;
  }
}

__global__ void k_prep_A32c0(const float* __restrict__ wd1, const float* __restrict__ ws1,
                             const float* __restrict__ Hm, const float* __restrict__ G,
                             const float* __restrict__ wf,
                             const float* __restrict__ bd1, const float* __restrict__ bs1,
                             const float* __restrict__ bd2, const float* __restrict__ bs2,
                             const float* __restrict__ bd3, const float* __restrict__ bf,
                             float* __restrict__ A3, float* __restrict__ A2,
                             float* __restrict__ c0) {
  int id = blockIdx.x * 256 + threadIdx.x;
  if (id < 16384) {
    int k = id & 127, c = id >> 7;
    float s = 0.f;
    for (int j = 0; j < 128; ++j) s = fmaf(wd1[c * 128 + j], Hm[j * 128 + k], s);
    A3[c * 128 + k] = s;
  } else if (id < 16384 + 8192) {
    int idx = id - 16384;
    int k = idx & 127, c = idx >> 7;   // c < 64
    float s = 0.f;
    for (int o = 0; o < 64; ++o)
      s = fmaf(ws1[c * 64 + o], Hm[(2 * o) * 128 + k] + Hm[(2 * o + 1) * 128 + k], s);
    A2[c * 128 + k] = s;
  } else if (id < 16384 + 8192 + 128) {
    int k = id - 16384 - 8192;
    float s = bf[k];
    for (int o = 0; o < 64; ++o) {
      float b = bd1[o] + bs1[o];
      s = fmaf(b, Hm[(o * 2) * 128 + k] + Hm[(o * 2 + 1) * 128 + k], s);
    }
    for (int o = 0; o < 32; ++o) {
      float b = bd2[o] + bs2[o];
      float g = G[(o * 4) * 128 + k] + G[(o * 4 + 1) * 128 + k] +
                G[(o * 4 + 2) * 128 + k] + G[(o * 4 + 3) * 128 + k];
      s = fmaf(b, g, s);
    }
    for (int o = 0; o < 32; ++o) {
      float w8 = 0.f;
      for (int j = 0; j < 8; ++j) w8 += wf[(o * 8 + j) * 128 + k];
      s = fmaf(bd3[o], w8, s);
    }
    c0[k] = s;
  }
}

// ---------------- per-node GEMM, W staged in LDS ----------------
template <int CIN, int COUT, bool BIAS, bool RELU>
__launch_bounds__(256)
__global__ void k_gemm(const float* __restrict__ X, const float* __restrict__ W,
                       const float* __restrict__ bias, float* __restrict__ Y) {
  static_assert(256 % COUT == 0, "");
  __shared__ float sW[CIN * COUT];
  for (int i = threadIdx.x; i < CIN * COUT; i += 256) sW[i] = W[i];
  __syncthreads();
  constexpr int RPB = 256 / COUT;
  int k = threadIdx.x % COUT;
  int r = threadIdx.x / COUT;
  int n = blockIdx.x * RPB + r;
  if (n >= NN) return;
  const float* xr = X + (size_t)n * CIN;
  float acc = BIAS ? bias[k] : 0.0f;
#pragma unroll
  for (int c4 = 0; c4 < CIN / 4; ++c4) {
    float4 xv = *reinterpret_cast<const float4*>(xr + c4 * 4);
    acc = fmaf(xv.x, sW[(c4 * 4 + 0) * COUT + k], acc);
    acc = fmaf(xv.y, sW[(c4 * 4 + 1) * COUT + k], acc);
    acc = fmaf(xv.z, sW[(c4 * 4 + 2) * COUT + k], acc);
    acc = fmaf(xv.w, sW[(c4 * 4 + 3) * COUT + k], acc);
  }
  if (RELU) acc = fmaxf(acc, 0.0f);
  Y[(size_t)n * COUT + k] = acc;
}

// ---------------- CSR gather: Z[n] = 2*dinv[n]^2*H[n] + sum_e coef*H[src] ----------------
template <int F>
__launch_bounds__(256)
__global__ void k_gather(const float* __restrict__ H, const int* __restrict__ esrc,
                         const float* __restrict__ ecoef, const int* __restrict__ row_start,
                         const float* __restrict__ dinv, float* __restrict__ Z) {
  constexpr int NPB = 256 / F;
  int n = blockIdx.x * NPB + threadIdx.x / F;
  int k = threadIdx.x % F;
  float dv = dinv[n];
  float acc = 2.0f * dv * dv * H[(size_t)n * F + k];
  int beg = row_start[n], end = row_start[n + 1];
  for (int i = beg; i < end; ++i) {
    int s = esrc[i];
    float c = ecoef[i];
    acc = fmaf(c, H[(size_t)s * F + k], acc);
  }
  Z[(size_t)n * F + k] = acc;
}

// ---------------- fused decoder: out = x3@A3 + x2@A2 + x1@A1 + c0 ----------------
__launch_bounds__(256)
__global__ void k_final(const float* __restrict__ x1, const float* __restrict__ x2,
                        const float* __restrict__ A1, const float* __restrict__ A2,
                        const float* __restrict__ A3, const float* __restrict__ c0,
                        float* __restrict__ io) {
  __shared__ float sx3[8][128];
  __shared__ float sx2[8][64];
  __shared__ float sx1[8][32];
  int n0 = blockIdx.x * 8;
  for (int i = threadIdx.x; i < 8 * 128; i += 256)
    sx3[i >> 7][i & 127] = io[(size_t)(n0 + (i >> 7)) * 128 + (i & 127)];
  for (int i = threadIdx.x; i < 8 * 64; i += 256)
    sx2[i >> 6][i & 63] = x2[(size_t)(n0 + (i >> 6)) * 64 + (i & 63)];
  for (int i = threadIdx.x; i < 8 * 32; i += 256)
    sx1[i >> 5][i & 31] = x1[(size_t)(n0 + (i >> 5)) * 32 + (i & 31)];
  __syncthreads();
  int lane = threadIdx.x & 31;
  int r = threadIdx.x >> 5;  // row 0..7
  int k = lane * 4;
  float4 acc = *reinterpret_cast<const float4*>(c0 + k);
#pragma unroll 4
  for (int c = 0; c < 128; ++c) {
    float xv = sx3[r][c];
    float4 a = *reinterpret_cast<const float4*>(A3 + c * 128 + k);
    acc.x = fmaf(xv, a.x, acc.x);
    acc.y = fmaf(xv, a.y, acc.y);
    acc.z = fmaf(xv, a.z, acc.z);
    acc.w = fmaf(xv, a.w, acc.w);
  }
#pragma unroll 4
  for (int c = 0; c < 64; ++c) {
    float xv = sx2[r][c];
    float4 a = *reinterpret_cast<const float4*>(A2 + c * 128 + k);
    acc.x = fmaf(xv, a.x, acc.x);
    acc.y = fmaf(xv, a.y, acc.y);
    acc.z = fmaf(xv, a.z, acc.z);
    acc.w = fmaf(xv, a.w, acc.w);
  }
#pragma unroll 4
  for (int c = 0; c < 32; ++c) {
    float xv = sx1[r][c];
    float4 a = *reinterpret_cast<const float4*>(A1 + c * 128 + k);
    acc.x = fmaf(xv, a.x, acc.x);
    acc.y = fmaf(xv, a.y, acc.y);
    acc.z = fmaf(xv, a.z, acc.z);
    acc.w = fmaf(xv, a.w, acc.w);
  }
  *reinterpret_cast<float4*>(io + (size_t)(n0 + r) * 128 + k) = acc;
}

extern "C" void kernel_launch(void* const* d_in, const int* in_sizes, int n_in,
                              void* d_out, int out_size, void* d_ws, size_t ws_size,
                              hipStream_t stream) {
  const float* x   = (const float*)d_in[0];
  const int* ei    = (const int*)d_in[1];
  const int* srcv  = ei;
  const int* dstv  = ei + NE;
  const float* w1  = (const float*)d_in[2];
  const float* b1  = (const float*)d_in[3];
  const float* fw1 = (const float*)d_in[4];
  const float* fb1 = (const float*)d_in[5];
  const float* w2  = (const float*)d_in[6];
  const float* b2  = (const float*)d_in[7];
  const float* fw2 = (const float*)d_in[8];
  const float* fb2 = (const float*)d_in[9];
  const float* w3  = (const float*)d_in[10];
  const float* b3  = (const float*)d_in[11];
  const float* fw3 = (const float*)d_in[12];
  const float* fb3 = (const float*)d_in[13];
  const float* wd1 = (const float*)d_in[14];
  const float* bd1 = (const float*)d_in[15];
  const float* wd2 = (const float*)d_in[16];
  const float* bd2 = (const float*)d_in[17];
  const float* wd3 = (const float*)d_in[18];
  const float* bd3 = (const float*)d_in[19];
  const float* ws1 = (const float*)d_in[20];
  const float* bs1 = (const float*)d_in[21];
  const float* ws2 = (const float*)d_in[22];
  const float* bs2 = (const float*)d_in[23];
  const float* wf  = (const float*)d_in[24];
  const float* bf  = (const float*)d_in[25];

  float* fp = (float*)d_ws;
  float* dinv = fp;                  // 50176
  float* R    = dinv + 50176;        // N*64  (h1 | z1/z2 overlay, later z3 spans all)
  float* x1   = R + 3200000;         // N*32
  float* x2   = x1 + 1600000;        // N*64
  float* ecoef= x2 + 3200000;        // 800000
  float* Wc2  = ecoef + 800000;      // 2048
  float* Wc3  = Wc2 + 2048;          // 8192
  float* bc1  = Wc3 + 8192;          // 64
  float* bc2  = bc1 + 64;            // 64
  float* bc3  = bc2 + 64;            // 128
  float* G    = bc3 + 128;           // 16384
  float* Hm   = G + 16384;           // 16384
  float* A3   = Hm + 16384;          // 16384
  float* A2   = A3 + 16384;          // 8192
  float* A1   = A2 + 8192;           // 4096
  float* c0   = A1 + 4096;           // 256
  int* ip     = (int*)(c0 + 256);
  int* deg    = ip;                  // 50176
  int* row_start = deg + 50176;      // 50176 (uses NN+1)
  int* cursor = row_start + 50176;   // 50176
  int* esrc   = cursor + 50176;      // 800000
  int* blksum = esrc + 800000;       // 256
  int* blkoff = blksum + 256;        // 256

  float* h1 = R;                     // [N,32]
  float* z1 = R + 1600000;           // [N,32]
  float* z2 = R + 1600000;           // [N,32] (z1 dead by then)
  float* z3 = R;                     // [N,64] (h1,z2 dead by then)
  float* outp = (float*)d_out;       // x3 staged here, then final out

  // ---- CSR build ----
  hipMemsetAsync(deg, 0, NN * sizeof(int), stream);
  k_hist<<<(NE + 255) / 256, 256, 0, stream>>>(dstv, deg);
  k_blksum<<<NBLK, 256, 0, stream>>>(deg, blksum);
  k_blkscan<<<1, 256, 0, stream>>>(blksum, blkoff);
  k_scan3<<<NBLK, 256, 0, stream>>>(deg, blkoff, row_start, cursor, dinv);
  k_scatter<<<(NE + 255) / 256, 256, 0, stream>>>(srcv, dstv, dinv, cursor, esrc, ecoef);

  // ---- weight composition ----
  k_prep_misc<<<41, 256, 0, stream>>>(w2, fw2, w3, fw3, b1, fw1, fb1, b2, fb2, b3, fb3,
                                      Wc2, Wc3, bc1, bc2, bc3);
  k_prep_G<<<64, 256, 0, stream>>>(wd3, wf, G);
  k_prep_HA1<<<80, 256, 0, stream>>>(wd2, G, ws2, Hm, A1);
  k_prep_A32c0<<<97, 256, 0, stream>>>(wd1, ws1, Hm, G, wf, bd1, bs1, bd2, bs2, bd3, bf,
                                       A3, A2, c0);

  // ---- layer 1: h1 = x@w1; z1 = gather(h1); x1 = relu(z1@fw1 + bc1) ----
  k_gemm<128, 32, false, false><<<NN / 8, 256, 0, stream>>>(x, w1, nullptr, h1);
  k_gather<32><<<NN / 8, 256, 0, stream>>>(h1, esrc, ecoef, row_start, dinv, z1);
  k_gemm<32, 32, true, true><<<NN / 8, 256, 0, stream>>>(z1, fw1, bc1, x1);

  // ---- layer 2 (aggregate-first): z2 = gather(x1); x2 = relu(z2@Wc2 + bc2) ----
  k_gather<32><<<NN / 8, 256, 0, stream>>>(x1, esrc, ecoef, row_start, dinv, z2);
  k_gemm<32, 64, true, true><<<NN / 4, 256, 0, stream>>>(z2, Wc2, bc2, x2);

  // ---- layer 3 (aggregate-first): z3 = gather(x2); x3 = relu(z3@Wc3 + bc3) ----
  k_gather<64><<<NN / 4, 256, 0, stream>>>(x2, esrc, ecoef, row_start, dinv, z3);
  k_gemm<64, 128, true, true><<<NN / 2, 256, 0, stream>>>(z3, Wc3, bc3, outp);

  // ---- fused decoder ----
  k_final<<<NN / 8, 256, 0, stream>>>(x1, x2, A1, A2, A3, c0, outp);
}

// Round 3
// 416.760 us; speedup vs baseline: 4.1706x; 1.4329x over previous
//
#include <hip/hip_runtime.h>

#define NN 50000
#define NE 800000
#define NBLK 196  // ceil(NN/256)

// ---------------- CSR build ----------------
__global__ void k_hist(const int* __restrict__ dst, int* __restrict__ deg) {
  int e = blockIdx.x * 256 + threadIdx.x;
  if (e < NE) atomicAdd(&deg[dst[e]], 1);
}

__global__ void k_blksum(const int* __restrict__ deg, int* __restrict__ blksum) {
  __shared__ int s[256];
  int n = blockIdx.x * 256 + threadIdx.x;
  s[threadIdx.x] = (n < NN) ? deg[n] : 0;
  __syncthreads();
  for (int off = 128; off > 0; off >>= 1) {
    if (threadIdx.x < off) s[threadIdx.x] += s[threadIdx.x + off];
    __syncthreads();
  }
  if (threadIdx.x == 0) blksum[blockIdx.x] = s[0];
}

__global__ void k_blkscan(const int* __restrict__ blksum, int* __restrict__ blkoff) {
  __shared__ int s[256];
  int t = threadIdx.x;
  int v0 = (t < NBLK) ? blksum[t] : 0;
  s[t] = v0;
  __syncthreads();
  for (int off = 1; off < 256; off <<= 1) {
    int v = (t >= off) ? s[t - off] : 0;
    __syncthreads();
    s[t] += v;
    __syncthreads();
  }
  if (t < NBLK) blkoff[t] = s[t] - v0;  // exclusive
}

__global__ void k_scan3(const int* __restrict__ deg, const int* __restrict__ blkoff,
                        int* __restrict__ row_start, int* __restrict__ cursor,
                        float* __restrict__ dinv) {
  __shared__ int s[256];
  int n = blockIdx.x * 256 + threadIdx.x;
  int d = (n < NN) ? deg[n] : 0;
  s[threadIdx.x] = d;
  __syncthreads();
  for (int off = 1; off < 256; off <<= 1) {
    int v = (threadIdx.x >= off) ? s[threadIdx.x - off] : 0;
    __syncthreads();
    s[threadIdx.x] += v;
    __syncthreads();
  }
  if (n < NN) {
    int rs = blkoff[blockIdx.x] + s[threadIdx.x] - d;
    row_start[n] = rs;
    cursor[n] = rs;
    dinv[n] = rsqrtf((float)d + 2.0f);
  }
  if (n == 0) row_start[NN] = NE;
}

__global__ void k_scatter(const int* __restrict__ srcv, const int* __restrict__ dstv,
                          const float* __restrict__ dinv, int* __restrict__ cursor,
                          int* __restrict__ esrc, float* __restrict__ ecoef) {
  int e = blockIdx.x * 256 + threadIdx.x;
  if (e >= NE) return;
  int s = srcv[e], d = dstv[e];
  int pos = atomicAdd(&cursor[d], 1);
  esrc[pos] = s;
  ecoef[pos] = dinv[s] * dinv[d];
}

// ---------------- weight composition (tiny) ----------------
__global__ void k_prep_misc(const float* __restrict__ w2, const float* __restrict__ fw2,
                            const float* __restrict__ w3, const float* __restrict__ fw3,
                            const float* __restrict__ b1, const float* __restrict__ fw1,
                            const float* __restrict__ fb1,
                            const float* __restrict__ b2, const float* __restrict__ fb2,
                            const float* __restrict__ b3, const float* __restrict__ fb3,
                            float* __restrict__ Wc2, float* __restrict__ Wc3,
                            float* __restrict__ bc1, float* __restrict__ bc2,
                            float* __restrict__ bc3) {
  int id = blockIdx.x * 256 + threadIdx.x;
  if (id < 2048) {                       // Wc2 [32,64]
    int c = id >> 6, k = id & 63;
    float s = 0.f;
    for (int j = 0; j < 64; ++j) s = fmaf(w2[c * 64 + j], fw2[j * 64 + k], s);
    Wc2[id] = s;
  } else if (id < 10240) {               // Wc3 [64,128]
    int idx = id - 2048;
    int c = idx >> 7, k = idx & 127;
    float s = 0.f;
    for (int j = 0; j < 128; ++j) s = fmaf(w3[c * 128 + j], fw3[j * 128 + k], s);
    Wc3[idx] = s;
  } else if (id < 10272) {               // bc1 [32]
    int k = id - 10240;
    float s = fb1[k];
    for (int j = 0; j < 32; ++j) s = fmaf(b1[j], fw1[j * 32 + k], s);
    bc1[k] = s;
  } else if (id < 10336) {               // bc2 [64]
    int k = id - 10272;
    float s = fb2[k];
    for (int j = 0; j < 64; ++j) s = fmaf(b2[j], fw2[j * 64 + k], s);
    bc2[k] = s;
  } else if (id < 10464) {               // bc3 [128]
    int k = id - 10336;
    float s = fb3[k];
    for (int j = 0; j < 128; ++j) s = fmaf(b3[j], fw3[j * 128 + k], s);
    bc3[k] = s;
  }
}

__global__ void k_prep_G(const float* __restrict__ wd3, const float* __restrict__ wf,
                         float* __restrict__ G) {
  int id = blockIdx.x * 256 + threadIdx.x;
  if (id >= 16384) return;
  int k = id & 127, r = id >> 7;
  int c = r >> 2, l = r & 3;
  float s = 0.f;
  for (int o = 0; o < 32; ++o) {
    s = fmaf(wd3[c * 64 + o * 2 + 0], wf[(o * 8 + 2 * l + 0) * 128 + k], s);
    s = fmaf(wd3[c * 64 + o * 2 + 1], wf[(o * 8 + 2 * l + 1) * 128 + k], s);
  }
  G[r * 128 + k] = s;
}

__global__ void k_prep_HA1(const float* __restrict__ wd2, const float* __restrict__ G,
                           const float* __restrict__ ws2,
                           float* __restrict__ Hm, float* __restrict__ A1) {
  int id = blockIdx.x * 256 + threadIdx.x;
  if (id < 16384) {
    int k = id & 127, r = id >> 7;
    int c = r >> 1, l = r & 1;
    float s = 0.f;
    for (int o = 0; o < 32; ++o) {
      s = fmaf(wd2[c * 64 + o * 2 + 0], G[(o * 4 + 2 * l + 0) * 128 + k], s);
      s = fmaf(wd2[c * 64 + o * 2 + 1], G[(o * 4 + 2 * l + 1) * 128 + k], s);
    }
    Hm[r * 128 + k] = s;
  } else if (id < 16384 + 4096) {
    int idx = id - 16384;
    int k = idx & 127, c = idx >> 7;   // c < 32
    float s = 0.f;
    for (int o = 0; o < 32; ++o) {
      float g = G[(4 * o) * 128 + k] + G[(4 * o + 1) * 128 + k] +
                G[(4 * o + 2) * 128 + k] + G[(4 * o + 3) * 128 + k];
      s = fmaf(ws2[c * 32 + o], g, s);
    }
    A1[c * 128 + k] = s;
  }
}

__global__ void k_prep_A32c0(const float* __restrict__ wd1, const float* __restrict__ ws1,
                             const float* __restrict__ Hm, const float* __restrict__ G,
                             const float* __restrict__ wf,
                             const float* __restrict__ bd1, const float* __restrict__ bs1,
                             const float* __restrict__ bd2, const float* __restrict__ bs2,
                             const float* __restrict__ bd3, const float* __restrict__ bf,
                             float* __restrict__ A3, float* __restrict__ A2,
                             float* __restrict__ c0) {
  int id = blockIdx.x * 256 + threadIdx.x;
  if (id < 16384) {
    int k = id & 127, c = id >> 7;
    float s = 0.f;
    for (int j = 0; j < 128; ++j) s = fmaf(wd1[c * 128 + j], Hm[j * 128 + k], s);
    A3[c * 128 + k] = s;
  } else if (id < 16384 + 8192) {
    int idx = id - 16384;
    int k = idx & 127, c = idx >> 7;   // c < 64
    float s = 0.f;
    for (int o = 0; o < 64; ++o)
      s = fmaf(ws1[c * 64 + o], Hm[(2 * o) * 128 + k] + Hm[(2 * o + 1) * 128 + k], s);
    A2[c * 128 + k] = s;
  } else if (id < 16384 + 8192 + 128) {
    int k = id - 16384 - 8192;
    float s = bf[k];
    for (int o = 0; o < 64; ++o) {
      float b = bd1[o] + bs1[o];
      s = fmaf(b, Hm[(o * 2) * 128 + k] + Hm[(o * 2 + 1) * 128 + k], s);
    }
    for (int o = 0; o < 32; ++o) {
      float b = bd2[o] + bs2[o];
      float g = G[(o * 4) * 128 + k] + G[(o * 4 + 1) * 128 + k] +
                G[(o * 4 + 2) * 128 + k] + G[(o * 4 + 3) * 128 + k];
      s = fmaf(b, g, s);
    }
    for (int o = 0; o < 32; ++o) {
      float w8 = 0.f;
      for (int j = 0; j < 8; ++j) w8 += wf[(o * 8 + j) * 128 + k];
      s = fmaf(bd3[o], w8, s);
    }
    c0[k] = s;
  }
}

// ---------------- per-node GEMM, W staged in LDS ----------------
template <int CIN, int COUT, bool BIAS, bool RELU>
__launch_bounds__(256)
__global__ void k_gemm(const float* __restrict__ X, const float* __restrict__ W,
                       const float* __restrict__ bias, float* __restrict__ Y) {
  static_assert(256 % COUT == 0, "");
  __shared__ float sW[CIN * COUT];
  for (int i = threadIdx.x; i < CIN * COUT; i += 256) sW[i] = W[i];
  __syncthreads();
  constexpr int RPB = 256 / COUT;
  int k = threadIdx.x % COUT;
  int r = threadIdx.x / COUT;
  int n = blockIdx.x * RPB + r;
  if (n >= NN) return;
  const float* xr = X + (size_t)n * CIN;
  float acc = BIAS ? bias[k] : 0.0f;
#pragma unroll
  for (int c4 = 0; c4 < CIN / 4; ++c4) {
    float4 xv = *reinterpret_cast<const float4*>(xr + c4 * 4);
    acc = fmaf(xv.x, sW[(c4 * 4 + 0) * COUT + k], acc);
    acc = fmaf(xv.y, sW[(c4 * 4 + 1) * COUT + k], acc);
    acc = fmaf(xv.z, sW[(c4 * 4 + 2) * COUT + k], acc);
    acc = fmaf(xv.w, sW[(c4 * 4 + 3) * COUT + k], acc);
  }
  if (RELU) acc = fmaxf(acc, 0.0f);
  Y[(size_t)n * COUT + k] = acc;
}

// ---------------- CSR gather (float4 lanes): Z[n] = 2*dinv^2*H[n] + sum coef*H[src] ----
template <int F>
__launch_bounds__(256)
__global__ void k_gather(const float* __restrict__ H, const int* __restrict__ esrc,
                         const float* __restrict__ ecoef, const int* __restrict__ row_start,
                         const float* __restrict__ dinv, float* __restrict__ Z) {
  constexpr int LPN = F / 4;        // lanes per node
  constexpr int NPB = 256 / LPN;    // nodes per block
  int n = blockIdx.x * NPB + threadIdx.x / LPN;
  int l = (threadIdx.x % LPN) * 4;
  if (n >= NN) return;
  float dv = dinv[n];
  float s2 = 2.0f * dv * dv;
  float4 h0 = *reinterpret_cast<const float4*>(H + (size_t)n * F + l);
  float4 acc = make_float4(s2 * h0.x, s2 * h0.y, s2 * h0.z, s2 * h0.w);
  int beg = row_start[n], end = row_start[n + 1];
  for (int i = beg; i < end; ++i) {
    int s = esrc[i];
    float c = ecoef[i];
    float4 hv = *reinterpret_cast<const float4*>(H + (size_t)s * F + l);
    acc.x = fmaf(c, hv.x, acc.x);
    acc.y = fmaf(c, hv.y, acc.y);
    acc.z = fmaf(c, hv.z, acc.z);
    acc.w = fmaf(c, hv.w, acc.w);
  }
  *reinterpret_cast<float4*>(Z + (size_t)n * F + l) = acc;
}

// ---------------- fused decoder as tiled GEMM: out = [x3|x2|x1] @ Acat + c0 ----------
// 32 rows x 128 cols per block, K=224 in 7 chunks of 32. x3 lives in io (= d_out);
// each block reads only its own 32 rows before overwriting them.
__launch_bounds__(256)
__global__ void k_final(const float* __restrict__ x1, const float* __restrict__ x2,
                        const float* __restrict__ Acat, const float* __restrict__ c0,
                        float* __restrict__ io) {
  __shared__ float sX[32][36];
  __shared__ float sA[32][128];
  int tid = threadIdx.x;
  int tc = tid & 31;        // col group: cols tc*4 .. tc*4+3
  int tr = tid >> 5;        // 0..7; rows tr, tr+8, tr+16, tr+24
  int n0 = blockIdx.x * 32;

  float4 cb = *reinterpret_cast<const float4*>(c0 + tc * 4);
  float4 acc0 = cb, acc1 = cb, acc2 = cb, acc3 = cb;

  int srow = tid >> 3;           // 0..31 (X staging row)
  int sc4 = (tid & 7) * 4;       // 0..28 (X staging col)
  int sn = n0 + srow;

  for (int ch = 0; ch < 7; ++ch) {
    // load X chunk to regs
    float4 xv = make_float4(0.f, 0.f, 0.f, 0.f);
    if (sn < NN) {
      if (ch < 4)
        xv = *reinterpret_cast<const float4*>(io + (size_t)sn * 128 + ch * 32 + sc4);
      else if (ch < 6)
        xv = *reinterpret_cast<const float4*>(x2 + (size_t)sn * 64 + (ch - 4) * 32 + sc4);
      else
        xv = *reinterpret_cast<const float4*>(x1 + (size_t)sn * 32 + sc4);
    }
    // load A chunk to regs (4 float4 per thread)
    float4 av[4];
#pragma unroll
    for (int j = 0; j < 4; ++j) {
      int idx = tid + j * 256;           // 0..1023
      int arow = idx >> 5, ac4 = (idx & 31) * 4;
      av[j] = *reinterpret_cast<const float4*>(Acat + (size_t)(ch * 32 + arow) * 128 + ac4);
    }
    __syncthreads();
    *reinterpret_cast<float4*>(&sX[srow][sc4]) = xv;
#pragma unroll
    for (int j = 0; j < 4; ++j) {
      int idx = tid + j * 256;
      int arow = idx >> 5, ac4 = (idx & 31) * 4;
      *reinterpret_cast<float4*>(&sA[arow][ac4]) = av[j];
    }
    __syncthreads();
#pragma unroll
    for (int k = 0; k < 32; ++k) {
      float4 a = *reinterpret_cast<const float4*>(&sA[k][tc * 4]);
      float xa = sX[tr][k];
      float xb = sX[tr + 8][k];
      float xc = sX[tr + 16][k];
      float xd = sX[tr + 24][k];
      acc0.x = fmaf(xa, a.x, acc0.x); acc0.y = fmaf(xa, a.y, acc0.y);
      acc0.z = fmaf(xa, a.z, acc0.z); acc0.w = fmaf(xa, a.w, acc0.w);
      acc1.x = fmaf(xb, a.x, acc1.x); acc1.y = fmaf(xb, a.y, acc1.y);
      acc1.z = fmaf(xb, a.z, acc1.z); acc1.w = fmaf(xb, a.w, acc1.w);
      acc2.x = fmaf(xc, a.x, acc2.x); acc2.y = fmaf(xc, a.y, acc2.y);
      acc2.z = fmaf(xc, a.z, acc2.z); acc2.w = fmaf(xc, a.w, acc2.w);
      acc3.x = fmaf(xd, a.x, acc3.x); acc3.y = fmaf(xd, a.y, acc3.y);
      acc3.z = fmaf(xd, a.z, acc3.z); acc3.w = fmaf(xd, a.w, acc3.w);
    }
  }
  int n;
  n = n0 + tr;      if (n < NN) *reinterpret_cast<float4*>(io + (size_t)n * 128 + tc * 4) = acc0;
  n = n0 + tr + 8;  if (n < NN) *reinterpret_cast<float4*>(io + (size_t)n * 128 + tc * 4) = acc1;
  n = n0 + tr + 16; if (n < NN) *reinterpret_cast<float4*>(io + (size_t)n * 128 + tc * 4) = acc2;
  n = n0 + tr + 24; if (n < NN) *reinterpret_cast<float4*>(io + (size_t)n * 128 + tc * 4) = acc3;
}

extern "C" void kernel_launch(void* const* d_in, const int* in_sizes, int n_in,
                              void* d_out, int out_size, void* d_ws, size_t ws_size,
                              hipStream_t stream) {
  const float* x   = (const float*)d_in[0];
  const int* ei    = (const int*)d_in[1];
  const int* srcv  = ei;
  const int* dstv  = ei + NE;
  const float* w1  = (const float*)d_in[2];
  const float* b1  = (const float*)d_in[3];
  const float* fw1 = (const float*)d_in[4];
  const float* fb1 = (const float*)d_in[5];
  const float* w2  = (const float*)d_in[6];
  const float* b2  = (const float*)d_in[7];
  const float* fw2 = (const float*)d_in[8];
  const float* fb2 = (const float*)d_in[9];
  const float* w3  = (const float*)d_in[10];
  const float* b3  = (const float*)d_in[11];
  const float* fw3 = (const float*)d_in[12];
  const float* fb3 = (const float*)d_in[13];
  const float* wd1 = (const float*)d_in[14];
  const float* bd1 = (const float*)d_in[15];
  const float* wd2 = (const float*)d_in[16];
  const float* bd2 = (const float*)d_in[17];
  const float* wd3 = (const float*)d_in[18];
  const float* bd3 = (const float*)d_in[19];
  const float* ws1 = (const float*)d_in[20];
  const float* bs1 = (const float*)d_in[21];
  const float* ws2 = (const float*)d_in[22];
  const float* bs2 = (const float*)d_in[23];
  const float* wf  = (const float*)d_in[24];
  const float* bf  = (const float*)d_in[25];

  float* fp = (float*)d_ws;
  float* dinv = fp;                  // 50176
  float* R    = dinv + 50176;        // N*64 overlay region
  float* x1   = R + 3200000;         // N*32
  float* x2   = x1 + 1600000;        // N*64
  float* ecoef= x2 + 3200000;        // 800000
  float* Wc2  = ecoef + 800000;      // 2048
  float* Wc3  = Wc2 + 2048;          // 8192
  float* bc1  = Wc3 + 8192;          // 64
  float* bc2  = bc1 + 64;            // 64
  float* bc3  = bc2 + 64;            // 128
  float* G    = bc3 + 128;           // 16384
  float* Hm   = G + 16384;           // 16384
  float* A3   = Hm + 16384;          // 16384  } Acat = A3|A2|A1 contiguous
  float* A2   = A3 + 16384;          // 8192   }
  float* A1   = A2 + 8192;           // 4096   }
  float* c0   = A1 + 4096;           // 256
  int* ip     = (int*)(c0 + 256);
  int* deg    = ip;                  // 50176
  int* row_start = deg + 50176;      // 50176 (uses NN+1)
  int* cursor = row_start + 50176;   // 50176
  int* esrc   = cursor + 50176;      // 800000
  int* blksum = esrc + 800000;       // 256
  int* blkoff = blksum + 256;        // 256

  float* h1 = R;                     // [N,32]
  float* z1 = R + 1600000;           // [N,32]
  float* z2 = R + 1600000;           // [N,32] (z1 dead by then)
  float* z3 = R;                     // [N,64] (h1,z2 dead by then)
  float* outp = (float*)d_out;       // x3 staged here, then final out

  // ---- CSR build ----
  hipMemsetAsync(deg, 0, NN * sizeof(int), stream);
  k_hist<<<(NE + 255) / 256, 256, 0, stream>>>(dstv, deg);
  k_blksum<<<NBLK, 256, 0, stream>>>(deg, blksum);
  k_blkscan<<<1, 256, 0, stream>>>(blksum, blkoff);
  k_scan3<<<NBLK, 256, 0, stream>>>(deg, blkoff, row_start, cursor, dinv);
  k_scatter<<<(NE + 255) / 256, 256, 0, stream>>>(srcv, dstv, dinv, cursor, esrc, ecoef);

  // ---- weight composition ----
  k_prep_misc<<<41, 256, 0, stream>>>(w2, fw2, w3, fw3, b1, fw1, fb1, b2, fb2, b3, fb3,
                                      Wc2, Wc3, bc1, bc2, bc3);
  k_prep_G<<<64, 256, 0, stream>>>(wd3, wf, G);
  k_prep_HA1<<<80, 256, 0, stream>>>(wd2, G, ws2, Hm, A1);
  k_prep_A32c0<<<97, 256, 0, stream>>>(wd1, ws1, Hm, G, wf, bd1, bs1, bd2, bs2, bd3, bf,
                                       A3, A2, c0);

  // ---- layer 1: h1 = x@w1; z1 = gather(h1); x1 = relu(z1@fw1 + bc1) ----
  k_gemm<128, 32, false, false><<<NN / 8, 256, 0, stream>>>(x, w1, nullptr, h1);
  k_gather<32><<<(NN + 31) / 32, 256, 0, stream>>>(h1, esrc, ecoef, row_start, dinv, z1);
  k_gemm<32, 32, true, true><<<NN / 8, 256, 0, stream>>>(z1, fw1, bc1, x1);

  // ---- layer 2 (aggregate-first): z2 = gather(x1); x2 = relu(z2@Wc2 + bc2) ----
  k_gather<32><<<(NN + 31) / 32, 256, 0, stream>>>(x1, esrc, ecoef, row_start, dinv, z2);
  k_gemm<32, 64, true, true><<<NN / 4, 256, 0, stream>>>(z2, Wc2, bc2, x2);

  // ---- layer 3 (aggregate-first): z3 = gather(x2); x3 = relu(z3@Wc3 + bc3) ----
  k_gather<64><<<(NN + 15) / 16, 256, 0, stream>>>(x2, esrc, ecoef, row_start, dinv, z3);
  k_gemm<64, 128, true, true><<<NN / 2, 256, 0, stream>>>(z3, Wc3, bc3, outp);

  // ---- fused decoder (tiled GEMM) ----
  k_final<<<(NN + 31) / 32, 256, 0, stream>>>(x1, x2, A3 /*Acat*/, c0, outp);
}

// Round 4
// 274.971 us; speedup vs baseline: 6.3212x; 1.5156x over previous
//
#include <hip/hip_runtime.h>

#define NN 50000
#define NE 800000
#define NBLK 196  // ceil(NN/256)

// ---------------- CSR build ----------------
__global__ void k_hist(const int* __restrict__ dst, int* __restrict__ deg) {
  int e = blockIdx.x * 256 + threadIdx.x;
  if (e < NE) atomicAdd(&deg[dst[e]], 1);
}

__global__ void k_blksum(const int* __restrict__ deg, int* __restrict__ blksum) {
  __shared__ int s[256];
  int n = blockIdx.x * 256 + threadIdx.x;
  s[threadIdx.x] = (n < NN) ? deg[n] : 0;
  __syncthreads();
  for (int off = 128; off > 0; off >>= 1) {
    if (threadIdx.x < off) s[threadIdx.x] += s[threadIdx.x + off];
    __syncthreads();
  }
  if (threadIdx.x == 0) blksum[blockIdx.x] = s[0];
}

__global__ void k_blkscan(const int* __restrict__ blksum, int* __restrict__ blkoff) {
  __shared__ int s[256];
  int t = threadIdx.x;
  int v0 = (t < NBLK) ? blksum[t] : 0;
  s[t] = v0;
  __syncthreads();
  for (int off = 1; off < 256; off <<= 1) {
    int v = (t >= off) ? s[t - off] : 0;
    __syncthreads();
    s[t] += v;
    __syncthreads();
  }
  if (t < NBLK) blkoff[t] = s[t] - v0;  // exclusive
}

__global__ void k_scan3(const int* __restrict__ deg, const int* __restrict__ blkoff,
                        int* __restrict__ row_start, int* __restrict__ cursor,
                        float* __restrict__ dinv) {
  __shared__ int s[256];
  int n = blockIdx.x * 256 + threadIdx.x;
  int d = (n < NN) ? deg[n] : 0;
  s[threadIdx.x] = d;
  __syncthreads();
  for (int off = 1; off < 256; off <<= 1) {
    int v = (threadIdx.x >= off) ? s[threadIdx.x - off] : 0;
    __syncthreads();
    s[threadIdx.x] += v;
    __syncthreads();
  }
  if (n < NN) {
    int rs = blkoff[blockIdx.x] + s[threadIdx.x] - d;
    row_start[n] = rs;
    cursor[n] = rs;
    dinv[n] = rsqrtf((float)d + 2.0f);
  }
  if (n == 0) row_start[NN] = NE;
}

__global__ void k_scatter(const int* __restrict__ srcv, const int* __restrict__ dstv,
                          const float* __restrict__ dinv, int* __restrict__ cursor,
                          int2* __restrict__ epk) {
  int e = blockIdx.x * 256 + threadIdx.x;
  if (e >= NE) return;
  int s = srcv[e], d = dstv[e];
  int pos = atomicAdd(&cursor[d], 1);
  epk[pos] = make_int2(s, __float_as_int(dinv[s] * dinv[d]));
}

// ---------------- weight composition (tiny) ----------------
__global__ void k_prep_misc(const float* __restrict__ w2, const float* __restrict__ fw2,
                            const float* __restrict__ w3, const float* __restrict__ fw3,
                            const float* __restrict__ b1, const float* __restrict__ fw1,
                            const float* __restrict__ fb1,
                            const float* __restrict__ b2, const float* __restrict__ fb2,
                            const float* __restrict__ b3, const float* __restrict__ fb3,
                            float* __restrict__ Wc2, float* __restrict__ Wc3,
                            float* __restrict__ bc1, float* __restrict__ bc2,
                            float* __restrict__ bc3) {
  int id = blockIdx.x * 256 + threadIdx.x;
  if (id < 2048) {                       // Wc2 [32,64]
    int c = id >> 6, k = id & 63;
    float s = 0.f;
    for (int j = 0; j < 64; ++j) s = fmaf(w2[c * 64 + j], fw2[j * 64 + k], s);
    Wc2[id] = s;
  } else if (id < 10240) {               // Wc3 [64,128]
    int idx = id - 2048;
    int c = idx >> 7, k = idx & 127;
    float s = 0.f;
    for (int j = 0; j < 128; ++j) s = fmaf(w3[c * 128 + j], fw3[j * 128 + k], s);
    Wc3[idx] = s;
  } else if (id < 10272) {               // bc1 [32]
    int k = id - 10240;
    float s = fb1[k];
    for (int j = 0; j < 32; ++j) s = fmaf(b1[j], fw1[j * 32 + k], s);
    bc1[k] = s;
  } else if (id < 10336) {               // bc2 [64]
    int k = id - 10272;
    float s = fb2[k];
    for (int j = 0; j < 64; ++j) s = fmaf(b2[j], fw2[j * 64 + k], s);
    bc2[k] = s;
  } else if (id < 10464) {               // bc3 [128]
    int k = id - 10336;
    float s = fb3[k];
    for (int j = 0; j < 128; ++j) s = fmaf(b3[j], fw3[j * 128 + k], s);
    bc3[k] = s;
  }
}

__global__ void k_prep_G(const float* __restrict__ wd3, const float* __restrict__ wf,
                         float* __restrict__ G) {
  int id = blockIdx.x * 256 + threadIdx.x;
  if (id >= 16384) return;
  int k = id & 127, r = id >> 7;
  int c = r >> 2, l = r & 3;
  float s = 0.f;
  for (int o = 0; o < 32; ++o) {
    s = fmaf(wd3[c * 64 + o * 2 + 0], wf[(o * 8 + 2 * l + 0) * 128 + k], s);
    s = fmaf(wd3[c * 64 + o * 2 + 1], wf[(o * 8 + 2 * l + 1) * 128 + k], s);
  }
  G[r * 128 + k] = s;
}

__global__ void k_prep_HA1(const float* __restrict__ wd2, const float* __restrict__ G,
                           const float* __restrict__ ws2,
                           float* __restrict__ Hm, float* __restrict__ A1) {
  int id = blockIdx.x * 256 + threadIdx.x;
  if (id < 16384) {
    int k = id & 127, r = id >> 7;
    int c = r >> 1, l = r & 1;
    float s = 0.f;
    for (int o = 0; o < 32; ++o) {
      s = fmaf(wd2[c * 64 + o * 2 + 0], G[(o * 4 + 2 * l + 0) * 128 + k], s);
      s = fmaf(wd2[c * 64 + o * 2 + 1], G[(o * 4 + 2 * l + 1) * 128 + k], s);
    }
    Hm[r * 128 + k] = s;
  } else if (id < 16384 + 4096) {
    int idx = id - 16384;
    int k = idx & 127, c = idx >> 7;   // c < 32
    float s = 0.f;
    for (int o = 0; o < 32; ++o) {
      float g = G[(4 * o) * 128 + k] + G[(4 * o + 1) * 128 + k] +
                G[(4 * o + 2) * 128 + k] + G[(4 * o + 3) * 128 + k];
      s = fmaf(ws2[c * 32 + o], g, s);
    }
    A1[c * 128 + k] = s;
  }
}

__global__ void k_prep_A32c0(const float* __restrict__ wd1, const float* __restrict__ ws1,
                             const float* __restrict__ Hm, const float* __restrict__ G,
                             const float* __restrict__ wf,
                             const float* __restrict__ bd1, const float* __restrict__ bs1,
                             const float* __restrict__ bd2, const float* __restrict__ bs2,
                             const float* __restrict__ bd3, const float* __restrict__ bf,
                             float* __restrict__ A3, float* __restrict__ A2,
                             float* __restrict__ c0) {
  int id = blockIdx.x * 256 + threadIdx.x;
  if (id < 16384) {
    int k = id & 127, c = id >> 7;
    float s = 0.f;
    for (int j = 0; j < 128; ++j) s = fmaf(wd1[c * 128 + j], Hm[j * 128 + k], s);
    A3[c * 128 + k] = s;
  } else if (id < 16384 + 8192) {
    int idx = id - 16384;
    int k = idx & 127, c = idx >> 7;   // c < 64
    float s = 0.f;
    for (int o = 0; o < 64; ++o)
      s = fmaf(ws1[c * 64 + o], Hm[(2 * o) * 128 + k] + Hm[(2 * o + 1) * 128 + k], s);
    A2[c * 128 + k] = s;
  } else if (id < 16384 + 8192 + 128) {
    int k = id - 16384 - 8192;
    float s = bf[k];
    for (int o = 0; o < 64; ++o) {
      float b = bd1[o] + bs1[o];
      s = fmaf(b, Hm[(o * 2) * 128 + k] + Hm[(o * 2 + 1) * 128 + k], s);
    }
    for (int o = 0; o < 32; ++o) {
      float b = bd2[o] + bs2[o];
      float g = G[(o * 4) * 128 + k] + G[(o * 4 + 1) * 128 + k] +
                G[(o * 4 + 2) * 128 + k] + G[(o * 4 + 3) * 128 + k];
      s = fmaf(b, g, s);
    }
    for (int o = 0; o < 32; ++o) {
      float w8 = 0.f;
      for (int j = 0; j < 8; ++j) w8 += wf[(o * 8 + j) * 128 + k];
      s = fmaf(bd3[o], w8, s);
    }
    c0[k] = s;
  }
}

// ---------------- layer-1 projection: h1 = x @ w1 (128->32), register-tiled ----------
__launch_bounds__(256)
__global__ void k_gemm1t(const float* __restrict__ X, const float* __restrict__ W,
                         float* __restrict__ Y) {
  __shared__ float sW[128 * 32];
  __shared__ float sXc[128 * 33];
  int t = threadIdx.x;
  int n0 = blockIdx.x * 128;
#pragma unroll
  for (int it = 0; it < 4; ++it) {          // stage full W (16 KB)
    int idx = t + it * 256;                  // 1024 float4 slots
    int kr = idx >> 3, c4 = (idx & 7) * 4;
    *reinterpret_cast<float4*>(&sW[kr * 32 + c4]) =
        *reinterpret_cast<const float4*>(&W[kr * 32 + c4]);
  }
  int rg = t >> 3;   // 0..31 -> rows 4rg..4rg+3
  int cg = t & 7;    // cols 4cg..4cg+3
  float acc[4][4];
#pragma unroll
  for (int r = 0; r < 4; ++r)
#pragma unroll
    for (int c = 0; c < 4; ++c) acc[r][c] = 0.f;

  for (int ch = 0; ch < 4; ++ch) {
    __syncthreads();
#pragma unroll
    for (int it = 0; it < 4; ++it) {        // stage X chunk [128 rows][32 k]
      int idx = t + it * 256;
      int row = idx & 127, k4 = (idx >> 7) * 4;
      int n = n0 + row;
      float4 v = make_float4(0.f, 0.f, 0.f, 0.f);
      if (n < NN) v = *reinterpret_cast<const float4*>(&X[(size_t)n * 128 + ch * 32 + k4]);
      sXc[row * 33 + k4 + 0] = v.x;
      sXc[row * 33 + k4 + 1] = v.y;
      sXc[row * 33 + k4 + 2] = v.z;
      sXc[row * 33 + k4 + 3] = v.w;
    }
    __syncthreads();
#pragma unroll
    for (int k = 0; k < 32; ++k) {
      float4 w = *reinterpret_cast<const float4*>(&sW[(ch * 32 + k) * 32 + cg * 4]);
#pragma unroll
      for (int r = 0; r < 4; ++r) {
        float xv = sXc[(rg * 4 + r) * 33 + k];
        acc[r][0] = fmaf(xv, w.x, acc[r][0]);
        acc[r][1] = fmaf(xv, w.y, acc[r][1]);
        acc[r][2] = fmaf(xv, w.z, acc[r][2]);
        acc[r][3] = fmaf(xv, w.w, acc[r][3]);
      }
    }
  }
#pragma unroll
  for (int r = 0; r < 4; ++r) {
    int n = n0 + rg * 4 + r;
    if (n < NN)
      *reinterpret_cast<float4*>(&Y[(size_t)n * 32 + cg * 4]) =
          make_float4(acc[r][0], acc[r][1], acc[r][2], acc[r][3]);
  }
}

// ---------------- fused gather(F=32) + GEMM 32->32 + relu ----------------
__launch_bounds__(256)
__global__ void k_fuse1(const float* __restrict__ H, const int2* __restrict__ epk,
                        const int* __restrict__ row_start, const float* __restrict__ dinv,
                        const float* __restrict__ W, const float* __restrict__ bias,
                        float* __restrict__ Y) {
  __shared__ float sZT[32 * 33];
  __shared__ float sW[32 * 32];
  int t = threadIdx.x;
  int n0 = blockIdx.x * 32;
  {  // stage W (4 KB)
    int kr = t >> 3, c4 = (t & 7) * 4;
    *reinterpret_cast<float4*>(&sW[kr * 32 + c4]) =
        *reinterpret_cast<const float4*>(&W[kr * 32 + c4]);
  }
  int node = t >> 3, lg = t & 7;
  int n = n0 + node;
  float4 acc = make_float4(0.f, 0.f, 0.f, 0.f);
  if (n < NN) {
    const float4* H4 = reinterpret_cast<const float4*>(H);
    float dv = dinv[n], s2 = 2.f * dv * dv;
    float4 h = H4[(size_t)n * 8 + lg];
    acc.x = s2 * h.x; acc.y = s2 * h.y; acc.z = s2 * h.z; acc.w = s2 * h.w;
    int beg = row_start[n], end = row_start[n + 1];
    int i = beg;
    for (; i + 1 < end; i += 2) {
      int2 p0 = epk[i], p1 = epk[i + 1];
      float c0f = __int_as_float(p0.y), c1f = __int_as_float(p1.y);
      float4 a = H4[(size_t)p0.x * 8 + lg];
      float4 b = H4[(size_t)p1.x * 8 + lg];
      acc.x = fmaf(c0f, a.x, acc.x); acc.y = fmaf(c0f, a.y, acc.y);
      acc.z = fmaf(c0f, a.z, acc.z); acc.w = fmaf(c0f, a.w, acc.w);
      acc.x = fmaf(c1f, b.x, acc.x); acc.y = fmaf(c1f, b.y, acc.y);
      acc.z = fmaf(c1f, b.z, acc.z); acc.w = fmaf(c1f, b.w, acc.w);
    }
    if (i < end) {
      int2 p = epk[i];
      float cf = __int_as_float(p.y);
      float4 a = H4[(size_t)p.x * 8 + lg];
      acc.x = fmaf(cf, a.x, acc.x); acc.y = fmaf(cf, a.y, acc.y);
      acc.z = fmaf(cf, a.z, acc.z); acc.w = fmaf(cf, a.w, acc.w);
    }
  }
  sZT[(lg * 4 + 0) * 33 + node] = acc.x;
  sZT[(lg * 4 + 1) * 33 + node] = acc.y;
  sZT[(lg * 4 + 2) * 33 + node] = acc.z;
  sZT[(lg * 4 + 3) * 33 + node] = acc.w;
  __syncthreads();
  int row = t >> 3, cg = t & 7;
  float4 bv = *reinterpret_cast<const float4*>(&bias[cg * 4]);
  float a0 = bv.x, a1 = bv.y, a2 = bv.z, a3 = bv.w;
#pragma unroll
  for (int k = 0; k < 32; ++k) {
    float xv = sZT[k * 33 + row];
    float4 w = *reinterpret_cast<const float4*>(&sW[k * 32 + cg * 4]);
    a0 = fmaf(xv, w.x, a0); a1 = fmaf(xv, w.y, a1);
    a2 = fmaf(xv, w.z, a2); a3 = fmaf(xv, w.w, a3);
  }
  int nn = n0 + row;
  if (nn < NN)
    *reinterpret_cast<float4*>(&Y[(size_t)nn * 32 + cg * 4]) =
        make_float4(fmaxf(a0, 0.f), fmaxf(a1, 0.f), fmaxf(a2, 0.f), fmaxf(a3, 0.f));
}

// ---------------- fused gather(F=32) + GEMM 32->64 + relu ----------------
__launch_bounds__(256)
__global__ void k_fuse2(const float* __restrict__ H, const int2* __restrict__ epk,
                        const int* __restrict__ row_start, const float* __restrict__ dinv,
                        const float* __restrict__ W, const float* __restrict__ bias,
                        float* __restrict__ Y) {
  __shared__ float sZT[32 * 33];
  __shared__ float sW[32 * 64];
  int t = threadIdx.x;
  int n0 = blockIdx.x * 32;
#pragma unroll
  for (int it = 0; it < 2; ++it) {  // stage W (8 KB)
    int idx = t + it * 256;
    int kr = idx >> 4, c4 = (idx & 15) * 4;
    *reinterpret_cast<float4*>(&sW[kr * 64 + c4]) =
        *reinterpret_cast<const float4*>(&W[kr * 64 + c4]);
  }
  int node = t >> 3, lg = t & 7;
  int n = n0 + node;
  float4 acc = make_float4(0.f, 0.f, 0.f, 0.f);
  if (n < NN) {
    const float4* H4 = reinterpret_cast<const float4*>(H);
    float dv = dinv[n], s2 = 2.f * dv * dv;
    float4 h = H4[(size_t)n * 8 + lg];
    acc.x = s2 * h.x; acc.y = s2 * h.y; acc.z = s2 * h.z; acc.w = s2 * h.w;
    int beg = row_start[n], end = row_start[n + 1];
    int i = beg;
    for (; i + 1 < end; i += 2) {
      int2 p0 = epk[i], p1 = epk[i + 1];
      float c0f = __int_as_float(p0.y), c1f = __int_as_float(p1.y);
      float4 a = H4[(size_t)p0.x * 8 + lg];
      float4 b = H4[(size_t)p1.x * 8 + lg];
      acc.x = fmaf(c0f, a.x, acc.x); acc.y = fmaf(c0f, a.y, acc.y);
      acc.z = fmaf(c0f, a.z, acc.z); acc.w = fmaf(c0f, a.w, acc.w);
      acc.x = fmaf(c1f, b.x, acc.x); acc.y = fmaf(c1f, b.y, acc.y);
      acc.z = fmaf(c1f, b.z, acc.z); acc.w = fmaf(c1f, b.w, acc.w);
    }
    if (i < end) {
      int2 p = epk[i];
      float cf = __int_as_float(p.y);
      float4 a = H4[(size_t)p.x * 8 + lg];
      acc.x = fmaf(cf, a.x, acc.x); acc.y = fmaf(cf, a.y, acc.y);
      acc.z = fmaf(cf, a.z, acc.z); acc.w = fmaf(cf, a.w, acc.w);
    }
  }
  sZT[(lg * 4 + 0) * 33 + node] = acc.x;
  sZT[(lg * 4 + 1) * 33 + node] = acc.y;
  sZT[(lg * 4 + 2) * 33 + node] = acc.z;
  sZT[(lg * 4 + 3) * 33 + node] = acc.w;
  __syncthreads();
  int r2 = t >> 4, cg = t & 15;  // rows r2, r2+16; cols 4cg..
  float4 bv = *reinterpret_cast<const float4*>(&bias[cg * 4]);
  float a0 = bv.x, a1 = bv.y, a2 = bv.z, a3 = bv.w;
  float b0 = bv.x, b1 = bv.y, b2 = bv.z, b3 = bv.w;
#pragma unroll
  for (int k = 0; k < 32; ++k) {
    float x0 = sZT[k * 33 + r2];
    float x1v = sZT[k * 33 + r2 + 16];
    float4 w = *reinterpret_cast<const float4*>(&sW[k * 64 + cg * 4]);
    a0 = fmaf(x0, w.x, a0); a1 = fmaf(x0, w.y, a1);
    a2 = fmaf(x0, w.z, a2); a3 = fmaf(x0, w.w, a3);
    b0 = fmaf(x1v, w.x, b0); b1 = fmaf(x1v, w.y, b1);
    b2 = fmaf(x1v, w.z, b2); b3 = fmaf(x1v, w.w, b3);
  }
  int na = n0 + r2, nb = n0 + r2 + 16;
  if (na < NN)
    *reinterpret_cast<float4*>(&Y[(size_t)na * 64 + cg * 4]) =
        make_float4(fmaxf(a0, 0.f), fmaxf(a1, 0.f), fmaxf(a2, 0.f), fmaxf(a3, 0.f));
  if (nb < NN)
    *reinterpret_cast<float4*>(&Y[(size_t)nb * 64 + cg * 4]) =
        make_float4(fmaxf(b0, 0.f), fmaxf(b1, 0.f), fmaxf(b2, 0.f), fmaxf(b3, 0.f));
}

// ------- fused gather(F=64) + x3=relu(z@Wc3+bc3) + decoder out=[x3|x2|x1]@Acat+c0 -------
__launch_bounds__(256)
__global__ void k_fuse3(const float* __restrict__ X2, const float* __restrict__ X1,
                        const int2* __restrict__ epk, const int* __restrict__ row_start,
                        const float* __restrict__ dinv,
                        const float* __restrict__ W3, const float* __restrict__ bc3,
                        const float* __restrict__ Acat, const float* __restrict__ c0,
                        float* __restrict__ out) {
  __shared__ float sZT[64 * 33];    // z3 transposed [feat][node]; later reused as x-chunk [32][33]
  __shared__ float sX3[32 * 129];   // x3 tile [row][feat]
  __shared__ float sA[32 * 128];    // streamed W3/A chunks [k][col]
  int t = threadIdx.x;
  int n0 = blockIdx.x * 32;

  // ---- Phase A: gather F=64 ----
  {
    int node = t >> 3, lg = t & 7;
    int n = n0 + node;
    float4 alo = make_float4(0.f, 0.f, 0.f, 0.f), ahi = alo;
    if (n < NN) {
      const float4* H4 = reinterpret_cast<const float4*>(X2);
      float dv = dinv[n], s2 = 2.f * dv * dv;
      float4 h0 = H4[(size_t)n * 16 + lg];
      float4 h1v = H4[(size_t)n * 16 + 8 + lg];
      alo.x = s2 * h0.x; alo.y = s2 * h0.y; alo.z = s2 * h0.z; alo.w = s2 * h0.w;
      ahi.x = s2 * h1v.x; ahi.y = s2 * h1v.y; ahi.z = s2 * h1v.z; ahi.w = s2 * h1v.w;
      int beg = row_start[n], end = row_start[n + 1];
      int i = beg;
      for (; i + 1 < end; i += 2) {
        int2 p0 = epk[i], p1 = epk[i + 1];
        float c0f = __int_as_float(p0.y), c1f = __int_as_float(p1.y);
        float4 a0 = H4[(size_t)p0.x * 16 + lg];
        float4 a1 = H4[(size_t)p0.x * 16 + 8 + lg];
        float4 b0 = H4[(size_t)p1.x * 16 + lg];
        float4 b1 = H4[(size_t)p1.x * 16 + 8 + lg];
        alo.x = fmaf(c0f, a0.x, alo.x); alo.y = fmaf(c0f, a0.y, alo.y);
        alo.z = fmaf(c0f, a0.z, alo.z); alo.w = fmaf(c0f, a0.w, alo.w);
        ahi.x = fmaf(c0f, a1.x, ahi.x); ahi.y = fmaf(c0f, a1.y, ahi.y);
        ahi.z = fmaf(c0f, a1.z, ahi.z); ahi.w = fmaf(c0f, a1.w, ahi.w);
        alo.x = fmaf(c1f, b0.x, alo.x); alo.y = fmaf(c1f, b0.y, alo.y);
        alo.z = fmaf(c1f, b0.z, alo.z); alo.w = fmaf(c1f, b0.w, alo.w);
        ahi.x = fmaf(c1f, b1.x, ahi.x); ahi.y = fmaf(c1f, b1.y, ahi.y);
        ahi.z = fmaf(c1f, b1.z, ahi.z); ahi.w = fmaf(c1f, b1.w, ahi.w);
      }
      if (i < end) {
        int2 p = epk[i];
        float cf = __int_as_float(p.y);
        float4 a0 = H4[(size_t)p.x * 16 + lg];
        float4 a1 = H4[(size_t)p.x * 16 + 8 + lg];
        alo.x = fmaf(cf, a0.x, alo.x); alo.y = fmaf(cf, a0.y, alo.y);
        alo.z = fmaf(cf, a0.z, alo.z); alo.w = fmaf(cf, a0.w, alo.w);
        ahi.x = fmaf(cf, a1.x, ahi.x); ahi.y = fmaf(cf, a1.y, ahi.y);
        ahi.z = fmaf(cf, a1.z, ahi.z); ahi.w = fmaf(cf, a1.w, ahi.w);
      }
    }
    sZT[(lg * 4 + 0) * 33 + node] = alo.x;
    sZT[(lg * 4 + 1) * 33 + node] = alo.y;
    sZT[(lg * 4 + 2) * 33 + node] = alo.z;
    sZT[(lg * 4 + 3) * 33 + node] = alo.w;
    sZT[(lg * 4 + 32) * 33 + node] = ahi.x;
    sZT[(lg * 4 + 33) * 33 + node] = ahi.y;
    sZT[(lg * 4 + 34) * 33 + node] = ahi.z;
    sZT[(lg * 4 + 35) * 33 + node] = ahi.w;
  }

  int rg = t >> 5;   // 0..7 -> rows 4rg..4rg+3
  int cg = t & 31;   // cols 4cg..4cg+3

  // ---- Phase B: x3 = relu(z3 @ Wc3 + bc3) ----
  float xb[4][4];
  {
    float4 bv = *reinterpret_cast<const float4*>(&bc3[cg * 4]);
#pragma unroll
    for (int r = 0; r < 4; ++r) { xb[r][0] = bv.x; xb[r][1] = bv.y; xb[r][2] = bv.z; xb[r][3] = bv.w; }
  }
  for (int ch = 0; ch < 2; ++ch) {
    __syncthreads();
#pragma unroll
    for (int it = 0; it < 4; ++it) {
      int idx = t + it * 256;
      int kr = idx >> 5, c4 = (idx & 31) * 4;
      *reinterpret_cast<float4*>(&sA[kr * 128 + c4]) =
          *reinterpret_cast<const float4*>(&W3[(ch * 32 + kr) * 128 + c4]);
    }
    __syncthreads();
#pragma unroll
    for (int k = 0; k < 32; ++k) {
      float4 a = *reinterpret_cast<const float4*>(&sA[k * 128 + cg * 4]);
#pragma unroll
      for (int r = 0; r < 4; ++r) {
        float xv = sZT[(ch * 32 + k) * 33 + rg * 4 + r];
        xb[r][0] = fmaf(xv, a.x, xb[r][0]); xb[r][1] = fmaf(xv, a.y, xb[r][1]);
        xb[r][2] = fmaf(xv, a.z, xb[r][2]); xb[r][3] = fmaf(xv, a.w, xb[r][3]);
      }
    }
  }
#pragma unroll
  for (int r = 0; r < 4; ++r)
#pragma unroll
    for (int c = 0; c < 4; ++c)
      sX3[(rg * 4 + r) * 129 + cg * 4 + c] = fmaxf(xb[r][c], 0.f);

  // ---- Phase C: out = c0 + x3@A3 + x2@A2 + x1@A1 ----
  float o[4][4];
  {
    float4 cv = *reinterpret_cast<const float4*>(&c0[cg * 4]);
#pragma unroll
    for (int r = 0; r < 4; ++r) { o[r][0] = cv.x; o[r][1] = cv.y; o[r][2] = cv.z; o[r][3] = cv.w; }
  }
  for (int ch = 0; ch < 7; ++ch) {
    __syncthreads();
#pragma unroll
    for (int it = 0; it < 4; ++it) {
      int idx = t + it * 256;
      int kr = idx >> 5, c4 = (idx & 31) * 4;
      *reinterpret_cast<float4*>(&sA[kr * 128 + c4]) =
          *reinterpret_cast<const float4*>(&Acat[(ch * 32 + kr) * 128 + c4]);
    }
    if (ch >= 4) {  // stage x2/x1 chunk into sZT region as [32 rows][33]
      int row = t >> 3, k4 = (t & 7) * 4;
      int n = n0 + row;
      float4 v = make_float4(0.f, 0.f, 0.f, 0.f);
      if (n < NN) {
        if (ch < 6) v = *reinterpret_cast<const float4*>(&X2[(size_t)n * 64 + (ch - 4) * 32 + k4]);
        else        v = *reinterpret_cast<const float4*>(&X1[(size_t)n * 32 + k4]);
      }
      sZT[row * 33 + k4 + 0] = v.x;
      sZT[row * 33 + k4 + 1] = v.y;
      sZT[row * 33 + k4 + 2] = v.z;
      sZT[row * 33 + k4 + 3] = v.w;
    }
    __syncthreads();
    const float* xp = (ch < 4) ? &sX3[ch * 32] : &sZT[0];
    int xs = (ch < 4) ? 129 : 33;
#pragma unroll
    for (int k = 0; k < 32; ++k) {
      float4 a = *reinterpret_cast<const float4*>(&sA[k * 128 + cg * 4]);
#pragma unroll
      for (int r = 0; r < 4; ++r) {
        float xv = xp[(rg * 4 + r) * xs + k];
        o[r][0] = fmaf(xv, a.x, o[r][0]); o[r][1] = fmaf(xv, a.y, o[r][1]);
        o[r][2] = fmaf(xv, a.z, o[r][2]); o[r][3] = fmaf(xv, a.w, o[r][3]);
      }
    }
  }
#pragma unroll
  for (int r = 0; r < 4; ++r) {
    int n = n0 + rg * 4 + r;
    if (n < NN)
      *reinterpret_cast<float4*>(&out[(size_t)n * 128 + cg * 4]) =
          make_float4(o[r][0], o[r][1], o[r][2], o[r][3]);
  }
}

extern "C" void kernel_launch(void* const* d_in, const int* in_sizes, int n_in,
                              void* d_out, int out_size, void* d_ws, size_t ws_size,
                              hipStream_t stream) {
  const float* x   = (const float*)d_in[0];
  const int* ei    = (const int*)d_in[1];
  const int* srcv  = ei;
  const int* dstv  = ei + NE;
  const float* w1  = (const float*)d_in[2];
  const float* b1  = (const float*)d_in[3];
  const float* fw1 = (const float*)d_in[4];
  const float* fb1 = (const float*)d_in[5];
  const float* w2  = (const float*)d_in[6];
  const float* b2  = (const float*)d_in[7];
  const float* fw2 = (const float*)d_in[8];
  const float* fb2 = (const float*)d_in[9];
  const float* w3  = (const float*)d_in[10];
  const float* b3  = (const float*)d_in[11];
  const float* fw3 = (const float*)d_in[12];
  const float* fb3 = (const float*)d_in[13];
  const float* wd1 = (const float*)d_in[14];
  const float* bd1 = (const float*)d_in[15];
  const float* wd2 = (const float*)d_in[16];
  const float* bd2 = (const float*)d_in[17];
  const float* wd3 = (const float*)d_in[18];
  const float* bd3 = (const float*)d_in[19];
  const float* ws1 = (const float*)d_in[20];
  const float* bs1 = (const float*)d_in[21];
  const float* ws2 = (const float*)d_in[22];
  const float* bs2 = (const float*)d_in[23];
  const float* wf  = (const float*)d_in[24];
  const float* bf  = (const float*)d_in[25];

  float* fp = (float*)d_ws;
  float* dinv = fp;                  // 50176
  float* h1   = dinv + 50176;        // N*32
  float* x1   = h1 + 1600000;        // N*32
  float* x2   = x1 + 1600000;        // N*64
  float* Wc2  = x2 + 3200000;        // 2048
  float* Wc3  = Wc2 + 2048;          // 8192
  float* bc1  = Wc3 + 8192;          // 64
  float* bc2  = bc1 + 64;            // 64
  float* bc3  = bc2 + 64;            // 128
  float* G    = bc3 + 128;           // 16384
  float* Hm   = G + 16384;           // 16384
  float* A3   = Hm + 16384;          // 16384 } Acat = A3|A2|A1 contiguous
  float* A2   = A3 + 16384;          // 8192  }
  float* A1   = A2 + 8192;           // 4096  }
  float* c0   = A1 + 4096;           // 256
  int* ip     = (int*)(c0 + 256);
  int2* epk   = (int2*)ip;           // 800000 int2 (8B-aligned: all offsets even)
  int* deg    = ip + 1600000;        // 50176
  int* row_start = deg + 50176;      // 50176 (NN+1 used)
  int* cursor = row_start + 50176;   // 50176
  int* blksum = cursor + 50176;      // 256
  int* blkoff = blksum + 256;        // 256
  float* outp = (float*)d_out;

  // ---- CSR build ----
  hipMemsetAsync(deg, 0, NN * sizeof(int), stream);
  k_hist<<<(NE + 255) / 256, 256, 0, stream>>>(dstv, deg);
  k_blksum<<<NBLK, 256, 0, stream>>>(deg, blksum);
  k_blkscan<<<1, 256, 0, stream>>>(blksum, blkoff);
  k_scan3<<<NBLK, 256, 0, stream>>>(deg, blkoff, row_start, cursor, dinv);
  k_scatter<<<(NE + 255) / 256, 256, 0, stream>>>(srcv, dstv, dinv, cursor, epk);

  // ---- weight composition ----
  k_prep_misc<<<41, 256, 0, stream>>>(w2, fw2, w3, fw3, b1, fw1, fb1, b2, fb2, b3, fb3,
                                      Wc2, Wc3, bc1, bc2, bc3);
  k_prep_G<<<64, 256, 0, stream>>>(wd3, wf, G);
  k_prep_HA1<<<80, 256, 0, stream>>>(wd2, G, ws2, Hm, A1);
  k_prep_A32c0<<<97, 256, 0, stream>>>(wd1, ws1, Hm, G, wf, bd1, bs1, bd2, bs2, bd3, bf,
                                       A3, A2, c0);

  // ---- pipeline ----
  k_gemm1t<<<(NN + 127) / 128, 256, 0, stream>>>(x, w1, h1);
  k_fuse1<<<(NN + 31) / 32, 256, 0, stream>>>(h1, epk, row_start, dinv, fw1, bc1, x1);
  k_fuse2<<<(NN + 31) / 32, 256, 0, stream>>>(x1, epk, row_start, dinv, Wc2, bc2, x2);
  k_fuse3<<<(NN + 31) / 32, 256, 0, stream>>>(x2, x1, epk, row_start, dinv, Wc3, bc3,
                                              A3 /*Acat*/, c0, outp);
}